// Round 1
// 1613.721 us; speedup vs baseline: 1.0841x; 1.0841x over previous
//
#include <hip/hip_runtime.h>
#include <cstdint>
#include <cstddef>

#define B_SZ 8192
#define H_N  8
#define K_N  4096
#define D_N  1024
#define HD_N 128

typedef __attribute__((ext_vector_type(8))) short bf16x8;
typedef __attribute__((ext_vector_type(4))) float f32x4;

// async global->LDS, 16B per lane, linear LDS dest (wave-uniform base + lane*16)
#define GLOAD16(gp, lp)                                                        \
    __builtin_amdgcn_global_load_lds(                                          \
        (const __attribute__((address_space(1))) void*)(gp),                   \
        (__attribute__((address_space(3))) void*)(lp), 16, 0, 0)

// ---------- helpers ----------
__device__ __forceinline__ unsigned int ordf(float f) {
    unsigned int u = __float_as_uint(f);
    return (u & 0x80000000u) ? ~u : (u | 0x80000000u);
}

__device__ __forceinline__ unsigned long long shfl_xor_u64(unsigned long long v, int m) {
    int lo = (int)(unsigned int)v;
    int hi = (int)(unsigned int)(v >> 32);
    lo = __shfl_xor(lo, m, 64);
    hi = __shfl_xor(hi, m, 64);
    return ((unsigned long long)(unsigned int)hi << 32) | (unsigned int)lo;
}

__device__ __forceinline__ unsigned short f2bf(float f) {  // RNE fp32 -> bf16
    unsigned int u = __float_as_uint(f);
    u += 0x7FFFu + ((u >> 16) & 1u);
    return (unsigned short)(u >> 16);
}
__device__ __forceinline__ float bf2f(unsigned short s) {
    return __uint_as_float((unsigned int)s << 16);
}

// ---------- kernel 1: L2-normalize rows of 128 + split into bf16 hi/lo ----------
// Output row layout: 256 bf16 = [128 hi | 128 lo]. One wave per row.
// ZMODE=1: input rows are (b, h) from z (B, D); output row index = h*B + b.
// ZMODE=0: input rows are (h*K + n) from codebooks; output row index = same.
template<int ZMODE>
__global__ void normsplit_kernel(const float* __restrict__ in,
                                 unsigned short* __restrict__ out, int nrows) {
    int wid  = (int)((blockIdx.x * blockDim.x + threadIdx.x) >> 6);
    int lane = threadIdx.x & 63;
    if (wid >= nrows) return;
    const float* r;
    size_t orow;
    if (ZMODE) {
        int b = wid >> 3, h = wid & 7;
        r = in + (size_t)b * D_N + h * HD_N;
        orow = (size_t)h * B_SZ + b;
    } else {
        r = in + (size_t)wid * HD_N;
        orow = (size_t)wid;
    }
    float2 v = *(const float2*)(r + lane * 2);
    float ss = v.x * v.x + v.y * v.y;
#pragma unroll
    for (int m = 32; m; m >>= 1) ss += __shfl_xor(ss, m, 64);
    float d = fmaxf(sqrtf(ss), 1e-12f);
    float q0 = v.x / d, q1 = v.y / d;
    unsigned short h0 = f2bf(q0), h1 = f2bf(q1);
    float l0 = q0 - bf2f(h0), l1 = q1 - bf2f(h1);
    unsigned short* op = out + orow * 256;
    *(unsigned int*)(op + lane * 2) =
        (unsigned int)h0 | ((unsigned int)h1 << 16);
    *(unsigned int*)(op + 128 + lane * 2) =
        (unsigned int)f2bf(l0) | ((unsigned int)f2bf(l1) << 16);
}

// ---------- kernel 2: bf16-split MFMA GEMM (sims) + distances + atomic argmax ----
// fp32-accurate sims via 3xBF16: C = Ahi*Bhi + Alo*Bhi + Ahi*Blo, expressed as a
// K=384 bf16 GEMM: A' k-blocks [hi, lo, hi], B' k-blocks [hi, hi, lo].
// Tile 128x128, 4 waves (2x2), each wave 4x4 frags of mfma_f32_16x16x32_bf16.
// BK=64 per step, 6 steps. LDS chunk-major [kchunk][row][8] -> conflict-free
// ds_read_b128 (16-lane fragment reads are 256B contiguous). Staging uses
// global_load_lds width=16 with the chunk permutation applied to the global
// source address (LDS dest stays linear).
__global__ __launch_bounds__(256)
void sims_mfma_kernel(const unsigned short* __restrict__ zs,
                      const unsigned short* __restrict__ cs,
                      float* __restrict__ dist,
                      unsigned long long* __restrict__ packed) {
    __shared__ __align__(16) unsigned short As[8][128][8];  // 16 KB
    __shared__ __align__(16) unsigned short Bs[8][128][8];  // 16 KB

    const int bm = blockIdx.x, bn = blockIdx.y, h = blockIdx.z;
    const int t    = threadIdx.x;
    const int lane = t & 63;
    const int wid  = t >> 6;
    const int wm = wid >> 1, wn = wid & 1;     // 2x2 wave grid, 64x64 per wave
    const int cl = lane & 15, rg = lane >> 4;  // frag col / row-group

    const unsigned short* Ag = zs + ((size_t)h * B_SZ + (size_t)bm * 128) * 256;
    const unsigned short* Bg = cs + ((size_t)h * K_N  + (size_t)bn * 128) * 256;

    f32x4 acc[4][4];
#pragma unroll
    for (int i = 0; i < 4; ++i)
#pragma unroll
        for (int j = 0; j < 4; ++j) acc[i][j] = (f32x4)0.0f;

    for (int ks = 0; ks < 6; ++ks) {
        const int kb   = ks >> 1;
        const int kin  = (ks & 1) * 64;
        const int aoff = (kb == 1 ? 128 : 0) + kin;  // A': hi, lo, hi
        const int boff = (kb == 2 ? 128 : 0) + kin;  // B': hi, hi, lo
        // stage 128 rows x 64 bf16 for A and B: 1024 16B-chunks each,
        // 4 issues/thread/matrix; chunk f -> row r = f&127, kchunk c = f>>7
#pragma unroll
        for (int i = 0; i < 4; ++i) {
            const int f = t + i * 256;
            const int r = f & 127;
            const int c = f >> 7;  // 0..7
            GLOAD16(Ag + (size_t)r * 256 + aoff + c * 8, &As[0][0][0] + (size_t)f * 8);
            GLOAD16(Bg + (size_t)r * 256 + boff + c * 8, &Bs[0][0][0] + (size_t)f * 8);
        }
        __syncthreads();  // compiler drains vmcnt(0) before s_barrier

#pragma unroll
        for (int kk = 0; kk < 2; ++kk) {
            const int q = kk * 4 + rg;  // kchunk for this lane's fragment slice
            bf16x8 a[4], b[4];
#pragma unroll
            for (int mi = 0; mi < 4; ++mi)
                a[mi] = *(const bf16x8*)&As[q][wm * 64 + mi * 16 + cl][0];
#pragma unroll
            for (int ni = 0; ni < 4; ++ni)
                b[ni] = *(const bf16x8*)&Bs[q][wn * 64 + ni * 16 + cl][0];
#pragma unroll
            for (int mi = 0; mi < 4; ++mi)
#pragma unroll
                for (int ni = 0; ni < 4; ++ni)
                    acc[mi][ni] = __builtin_amdgcn_mfma_f32_16x16x32_bf16(
                        a[mi], b[ni], acc[mi][ni], 0, 0, 0);
        }
        __syncthreads();
    }

    // epilogue: dist = 1 - sim; argmax via packed u64 atomics.
    // C/D layout (m89/m91-verified): col = lane&15, row = (lane>>4)*4 + reg.
#pragma unroll
    for (int mi = 0; mi < 4; ++mi) {
#pragma unroll
        for (int j = 0; j < 4; ++j) {
            const int m = bm * 128 + wm * 64 + mi * 16 + rg * 4 + j;
            const size_t drow = ((size_t)m * H_N + h) * (size_t)K_N
                              + (size_t)bn * 128 + wn * 64;
            unsigned long long best = 0ull;
#pragma unroll
            for (int ni = 0; ni < 4; ++ni) {
                const float s = acc[mi][ni][j];
                dist[drow + ni * 16 + cl] = 1.0f - s;
                const int n = bn * 128 + wn * 64 + ni * 16 + cl;
                unsigned long long p =
                    ((unsigned long long)ordf(s) << 32) |
                    (unsigned int)(K_N - 1 - n);  // ties -> smallest n wins
                best = (p > best) ? p : best;
            }
            // reduce over the 16 lanes sharing this m (masks < 16 stay in-group)
#pragma unroll
            for (int ml = 1; ml < 16; ml <<= 1) {
                unsigned long long o = shfl_xor_u64(best, ml);
                best = (o > best) ? o : best;
            }
            if (cl == 0) {
                atomicMax(packed + (size_t)m * H_N + h, best);
            }
        }
    }
}

// ---------- kernel 3: decode indices, gather z_q ----------
__global__ void finalize_kernel(const unsigned long long* __restrict__ packed,
                                const float* __restrict__ z,
                                const float* __restrict__ cb,
                                float* __restrict__ zq,
                                float* __restrict__ idx_out) {
    int rid  = (int)((blockIdx.x * blockDim.x + threadIdx.x) >> 6);
    int lane = threadIdx.x & 63;
    if (rid >= B_SZ * H_N) return;
    int b = rid >> 3;
    int h = rid & 7;
    unsigned long long p = packed[rid];
    int idx = K_N - 1 - (int)(unsigned int)(p & 0xFFFFFFFFull);
    if (lane == 0) idx_out[rid] = (float)idx;
    const float* crow = cb + ((size_t)h * K_N + idx) * HD_N;
    const float* zrow = z + (size_t)b * D_N + h * HD_N;
    float2 c  = *(const float2*)(crow + lane * 2);
    float2 zr = *(const float2*)(zrow + lane * 2);
    float2 o;
    o.x = zr.x + (c.x - zr.x);  // replicate reference fp ops exactly
    o.y = zr.y + (c.y - zr.y);
    *(float2*)(zq + (size_t)b * D_N + h * HD_N + lane * 2) = o;
}

extern "C" void kernel_launch(void* const* d_in, const int* in_sizes, int n_in,
                              void* d_out, int out_size, void* d_ws, size_t ws_size,
                              hipStream_t stream) {
    const float* z  = (const float*)d_in[0];   // (B, D)
    const float* cb = (const float*)d_in[1];   // (H, K, HD)

    float* out  = (float*)d_out;
    float* zq   = out;                                     // B*D floats
    float* idxo = out + (size_t)B_SZ * D_N;                // B*H floats
    float* dist = idxo + (size_t)B_SZ * H_N;               // B*H*K floats

    // workspace: same total footprint as previous version (~50.8 MB)
    unsigned short* zs = (unsigned short*)d_ws;            // 8*8192*256 bf16 = 33.5 MB
    unsigned short* cs = zs + (size_t)H_N * B_SZ * 256;    // 8*4096*256 bf16 = 16.8 MB
    unsigned long long* packed =
        (unsigned long long*)(cs + (size_t)H_N * K_N * 256);  // B*H u64 (512 KB)

    hipMemsetAsync(packed, 0, (size_t)B_SZ * H_N * sizeof(unsigned long long), stream);

    normsplit_kernel<1><<<(B_SZ * H_N) / 4, 256, 0, stream>>>(z, zs, B_SZ * H_N);
    normsplit_kernel<0><<<(H_N * K_N) / 4, 256, 0, stream>>>(cb, cs, H_N * K_N);

    dim3 g(B_SZ / 128, K_N / 128, H_N);
    sims_mfma_kernel<<<g, 256, 0, stream>>>(zs, cs, dist, packed);

    finalize_kernel<<<(B_SZ * H_N) / 4, 256, 0, stream>>>(packed, z, cb, zq, idxo);
}

// Round 2
// 1600.303 us; speedup vs baseline: 1.0932x; 1.0084x over previous
//
#include <hip/hip_runtime.h>
#include <cstdint>
#include <cstddef>

#define B_SZ 8192
#define H_N  8
#define K_N  4096
#define D_N  1024
#define HD_N 128

typedef __attribute__((ext_vector_type(8))) short bf16x8;
typedef __attribute__((ext_vector_type(4))) float f32x4;

// async global->LDS, 16B per lane, linear LDS dest (wave-uniform base + lane*16)
#define GLOAD16(gp, lp)                                                        \
    __builtin_amdgcn_global_load_lds(                                          \
        (const __attribute__((address_space(1))) void*)(gp),                   \
        (__attribute__((address_space(3))) void*)(lp), 16, 0, 0)

// ---------- helpers ----------
__device__ __forceinline__ unsigned int ordf(float f) {
    unsigned int u = __float_as_uint(f);
    return (u & 0x80000000u) ? ~u : (u | 0x80000000u);
}

__device__ __forceinline__ unsigned long long shfl_xor_u64(unsigned long long v, int m) {
    int lo = (int)(unsigned int)v;
    int hi = (int)(unsigned int)(v >> 32);
    lo = __shfl_xor(lo, m, 64);
    hi = __shfl_xor(hi, m, 64);
    return ((unsigned long long)(unsigned int)hi << 32) | (unsigned int)lo;
}

__device__ __forceinline__ unsigned short f2bf(float f) {  // RNE fp32 -> bf16
    unsigned int u = __float_as_uint(f);
    u += 0x7FFFu + ((u >> 16) & 1u);
    return (unsigned short)(u >> 16);
}
__device__ __forceinline__ float bf2f(unsigned short s) {
    return __uint_as_float((unsigned int)s << 16);
}

// ---------- kernel 1: L2-normalize rows of 128 + split into bf16 hi/lo ----------
template<int ZMODE>
__global__ void normsplit_kernel(const float* __restrict__ in,
                                 unsigned short* __restrict__ out, int nrows) {
    int wid  = (int)((blockIdx.x * blockDim.x + threadIdx.x) >> 6);
    int lane = threadIdx.x & 63;
    if (wid >= nrows) return;
    const float* r;
    size_t orow;
    if (ZMODE) {
        int b = wid >> 3, h = wid & 7;
        r = in + (size_t)b * D_N + h * HD_N;
        orow = (size_t)h * B_SZ + b;
    } else {
        r = in + (size_t)wid * HD_N;
        orow = (size_t)wid;
    }
    float2 v = *(const float2*)(r + lane * 2);
    float ss = v.x * v.x + v.y * v.y;
#pragma unroll
    for (int m = 32; m; m >>= 1) ss += __shfl_xor(ss, m, 64);
    float d = fmaxf(sqrtf(ss), 1e-12f);
    float q0 = v.x / d, q1 = v.y / d;
    unsigned short h0 = f2bf(q0), h1 = f2bf(q1);
    float l0 = q0 - bf2f(h0), l1 = q1 - bf2f(h1);
    unsigned short* op = out + orow * 256;
    *(unsigned int*)(op + lane * 2) =
        (unsigned int)h0 | ((unsigned int)h1 << 16);
    *(unsigned int*)(op + 128 + lane * 2) =
        (unsigned int)f2bf(l0) | ((unsigned int)f2bf(l1) << 16);
}

// ---------- kernel 2: bf16-split MFMA GEMM + distances + atomic argmax ----------
// 3xBF16 fp32 emulation as K=384 bf16 GEMM: A' k-blocks [hi,lo,hi], B' [hi,hi,lo].
// 128x128 tile, 4 waves (2x2), 4x4 frags of mfma_f32_16x16x32_bf16, BK=64.
// 2-phase software pipeline (T3-minimum): double-buffered LDS, prefetch next
// tile's global_load_lds BEFORE current tile's compute, publish with ONE
// vmcnt(0)+s_barrier per iteration (raw barrier — no __syncthreads drain
// between stage-issue and compute).
__global__ __launch_bounds__(256)
void sims_mfma_kernel(const unsigned short* __restrict__ zs,
                      const unsigned short* __restrict__ cs,
                      float* __restrict__ dist,
                      unsigned long long* __restrict__ packed) {
    // chunk-major [kchunk(8)][row(128)][8 bf16], double-buffered: 2x16KB each
    __shared__ __align__(16) unsigned short As[2][8192];
    __shared__ __align__(16) unsigned short Bs[2][8192];

    const int bm = blockIdx.x, bn = blockIdx.y, h = blockIdx.z;
    const int t    = threadIdx.x;
    const int lane = t & 63;
    const int wid  = t >> 6;
    const int wm = wid >> 1, wn = wid & 1;     // 2x2 wave grid, 64x64 per wave
    const int cl = lane & 15, rg = lane >> 4;  // frag col / row-group

    const unsigned short* Ag = zs + ((size_t)h * B_SZ + (size_t)bm * 128) * 256;
    const unsigned short* Bg = cs + ((size_t)h * K_N  + (size_t)bn * 128) * 256;

    f32x4 acc[4][4];
#pragma unroll
    for (int i = 0; i < 4; ++i)
#pragma unroll
        for (int j = 0; j < 4; ++j) acc[i][j] = (f32x4)0.0f;

    // per-K-step source k-offsets (in bf16 elems within the 256-wide row)
    // A': hi,lo,hi  B': hi,hi,lo ; each split into two 64-wide halves
    const int aoffs[6] = {0, 64, 128, 192, 0, 64};
    const int boffs[6] = {0, 64, 0, 64, 128, 192};

    // stage 128 rows x 64 bf16 of A and B into buf: 1024 16B chunks each,
    // 4 issues/thread/matrix; chunk f -> row r=f&127, kchunk c=f>>7.
    // LDS dest linear in f => wave-uniform base + lane*16 (gload_lds rule).
    auto stage = [&](int buf, int ks) {
        const int ao = aoffs[ks], bo = boffs[ks];
#pragma unroll
        for (int i = 0; i < 4; ++i) {
            const int f = t + i * 256;
            const int r = f & 127;
            const int c = f >> 7;  // 0..7
            GLOAD16(Ag + (size_t)r * 256 + ao + c * 8, &As[buf][f * 8]);
            GLOAD16(Bg + (size_t)r * 256 + bo + c * 8, &Bs[buf][f * 8]);
        }
    };

    // prologue: fill buf0
    stage(0, 0);
    asm volatile("s_waitcnt vmcnt(0)" ::: "memory");
    __builtin_amdgcn_s_barrier();

#pragma unroll
    for (int ks = 0; ks < 6; ++ks) {
        const int cur = ks & 1;
        if (ks < 5) stage(cur ^ 1, ks + 1);  // issue next-tile loads first

        // compute current buffer (compiler inserts lgkmcnt for ds_read->MFMA)
#pragma unroll
        for (int kk = 0; kk < 2; ++kk) {
            const int q = kk * 4 + rg;  // kchunk for this lane's fragment slice
            bf16x8 a[4], b[4];
#pragma unroll
            for (int mi = 0; mi < 4; ++mi)
                a[mi] = *(const bf16x8*)&As[cur][(q * 128 + wm * 64 + mi * 16 + cl) * 8];
#pragma unroll
            for (int ni = 0; ni < 4; ++ni)
                b[ni] = *(const bf16x8*)&Bs[cur][(q * 128 + wn * 64 + ni * 16 + cl) * 8];
#pragma unroll
            for (int mi = 0; mi < 4; ++mi)
#pragma unroll
                for (int ni = 0; ni < 4; ++ni)
                    acc[mi][ni] = __builtin_amdgcn_mfma_f32_16x16x32_bf16(
                        a[mi], b[ni], acc[mi][ni], 0, 0, 0);
        }

        if (ks < 5) {
            // publish next buffer; previous end-barrier already guaranteed
            // everyone finished reading the buffer we just overwrote.
            asm volatile("s_waitcnt vmcnt(0)" ::: "memory");
            __builtin_amdgcn_s_barrier();
        }
    }

    // epilogue: dist = 1 - sim; argmax via packed u64 atomics.
    // C/D layout (m89/m91-verified): col = lane&15, row = (lane>>4)*4 + reg.
#pragma unroll
    for (int mi = 0; mi < 4; ++mi) {
#pragma unroll
        for (int j = 0; j < 4; ++j) {
            const int m = bm * 128 + wm * 64 + mi * 16 + rg * 4 + j;
            const size_t drow = ((size_t)m * H_N + h) * (size_t)K_N
                              + (size_t)bn * 128 + wn * 64;
            unsigned long long best = 0ull;
#pragma unroll
            for (int ni = 0; ni < 4; ++ni) {
                const float s = acc[mi][ni][j];
                dist[drow + ni * 16 + cl] = 1.0f - s;
                const int n = bn * 128 + wn * 64 + ni * 16 + cl;
                unsigned long long p =
                    ((unsigned long long)ordf(s) << 32) |
                    (unsigned int)(K_N - 1 - n);  // ties -> smallest n wins
                best = (p > best) ? p : best;
            }
#pragma unroll
            for (int ml = 1; ml < 16; ml <<= 1) {
                unsigned long long o = shfl_xor_u64(best, ml);
                best = (o > best) ? o : best;
            }
            if (cl == 0) {
                atomicMax(packed + (size_t)m * H_N + h, best);
            }
        }
    }
}

// ---------- kernel 3: decode indices, gather z_q ----------
__global__ void finalize_kernel(const unsigned long long* __restrict__ packed,
                                const float* __restrict__ z,
                                const float* __restrict__ cb,
                                float* __restrict__ zq,
                                float* __restrict__ idx_out) {
    int rid  = (int)((blockIdx.x * blockDim.x + threadIdx.x) >> 6);
    int lane = threadIdx.x & 63;
    if (rid >= B_SZ * H_N) return;
    int b = rid >> 3;
    int h = rid & 7;
    unsigned long long p = packed[rid];
    int idx = K_N - 1 - (int)(unsigned int)(p & 0xFFFFFFFFull);
    if (lane == 0) idx_out[rid] = (float)idx;
    const float* crow = cb + ((size_t)h * K_N + idx) * HD_N;
    const float* zrow = z + (size_t)b * D_N + h * HD_N;
    float2 c  = *(const float2*)(crow + lane * 2);
    float2 zr = *(const float2*)(zrow + lane * 2);
    float2 o;
    o.x = zr.x + (c.x - zr.x);  // replicate reference fp ops exactly
    o.y = zr.y + (c.y - zr.y);
    *(float2*)(zq + (size_t)b * D_N + h * HD_N + lane * 2) = o;
}

extern "C" void kernel_launch(void* const* d_in, const int* in_sizes, int n_in,
                              void* d_out, int out_size, void* d_ws, size_t ws_size,
                              hipStream_t stream) {
    const float* z  = (const float*)d_in[0];   // (B, D)
    const float* cb = (const float*)d_in[1];   // (H, K, HD)

    float* out  = (float*)d_out;
    float* zq   = out;                                     // B*D floats
    float* idxo = out + (size_t)B_SZ * D_N;                // B*H floats
    float* dist = idxo + (size_t)B_SZ * H_N;               // B*H*K floats

    unsigned short* zs = (unsigned short*)d_ws;            // 8*8192*256 bf16 = 33.5 MB
    unsigned short* cs = zs + (size_t)H_N * B_SZ * 256;    // 8*4096*256 bf16 = 16.8 MB
    unsigned long long* packed =
        (unsigned long long*)(cs + (size_t)H_N * K_N * 256);  // B*H u64 (512 KB)

    hipMemsetAsync(packed, 0, (size_t)B_SZ * H_N * sizeof(unsigned long long), stream);

    normsplit_kernel<1><<<(B_SZ * H_N) / 4, 256, 0, stream>>>(z, zs, B_SZ * H_N);
    normsplit_kernel<0><<<(H_N * K_N) / 4, 256, 0, stream>>>(cb, cs, H_N * K_N);

    dim3 g(B_SZ / 128, K_N / 128, H_N);
    sims_mfma_kernel<<<g, 256, 0, stream>>>(zs, cs, dist, packed);

    finalize_kernel<<<(B_SZ * H_N) / 4, 256, 0, stream>>>(packed, z, cb, zq, idxo);
}